// Round 15
// baseline (200.736 us; speedup 1.0000x reference)
//
#include <hip/hip_runtime.h>
#include <hip/hip_bf16.h>

// CCAM (fp32 in/out): x (16,1024,64,64), martx (4096,64).
// rows = B*C = 16384, N = 4096 spatial, KDIM = 64.
// energy[r][k] = sum_n x[r][n] * M[n][k]           (GEMM1, K=4096)
// att = softmax(alpha * (rowmax(energy) - energy))  (64-wide)
// out[r][n] = gamma * sum_k att[r][k]*M[n][k] + x[r][n]
//
// Round-15: WAVE-SPECIALIZED producer/consumer. vmcnt is per-wave, so a
// dedicated producer wave's load stream is never drained by consumer waves'
// compiler-inserted waits (the failure mode of rounds 4-6 DMA and 3/14 reg
// pipelines). Persistent 256 blocks (1/CU), 1024 threads:
//   waves 8-15: producers — stream row p of band b+1 (16 KB, sequential)
//               fp32->bf16 into the alternate LDS image
//   waves 0-7:  consumers — round-12 bodies: phase-1 energy, softmax,
//               all-lane RMW, col-slice store (never vmcnt-drained)
// 2 image buffers (8 x 8208 B each) + Ep = 132 KB LDS; raw s_barrier with
// lgkm-only drains; 8 bands per block, double-buffered.

using frag_ab = __attribute__((ext_vector_type(8))) short;   // 8 bf16
using f32x4   = __attribute__((ext_vector_type(4))) float;   // MFMA C/D

#define MFMA16(a, b, c) __builtin_amdgcn_mfma_f32_16x16x32_bf16((a), (b), (c), 0, 0, 0)
#define SBAR() __builtin_amdgcn_sched_barrier(0)

static __device__ __forceinline__ unsigned short f2bf_bits(float f) {
    __hip_bfloat16 h = __float2bfloat16(f);
    return *reinterpret_cast<const unsigned short*>(&h);
}
static __device__ __forceinline__ float bf2f(unsigned short u) {
    return __uint_as_float(((unsigned)u) << 16);
}
static __device__ __forceinline__ frag_ab load_frag(const __hip_bfloat16* p) {
    return *reinterpret_cast<const frag_ab*>(p);
}
static __device__ __forceinline__ frag_ab cvt2(float4 a, float4 b) {
    frag_ab r;
    r[0] = (short)f2bf_bits(a.x); r[1] = (short)f2bf_bits(a.y);
    r[2] = (short)f2bf_bits(a.z); r[3] = (short)f2bf_bits(a.w);
    r[4] = (short)f2bf_bits(b.x); r[5] = (short)f2bf_bits(b.y);
    r[6] = (short)f2bf_bits(b.z); r[7] = (short)f2bf_bits(b.w);
    return r;
}

// -------- kernel 0: build frag-linear B banks (unchanged, validated) --------
// MtF  (512 frags x 1 KB): frag f = slot*4+t, elem (lane,j) = M[32*slot+8g+j][16t+r15]
// MbfF (512 frags x 1 KB): frag f = nt*2+h,   elem (lane,j) = M[16nt+r15][32h+8g+j]
__global__ __launch_bounds__(256) void prep_frags(
        const float* __restrict__ M,
        __hip_bfloat16* __restrict__ MtF, __hip_bfloat16* __restrict__ MbfF) {
    const int w    = threadIdx.x >> 6;
    const int lane = threadIdx.x & 63;
    const int g    = lane >> 4;
    const int r15  = lane & 15;
    const int f    = blockIdx.x * 4 + w;    // 0..1023
    if (f < 512) {
        const int slot = f >> 2, t = f & 3;
        frag_ab fr;
#pragma unroll
        for (int j = 0; j < 8; ++j)
            fr[j] = (short)f2bf_bits(M[(size_t)(32 * slot + 8 * g + j) * 64 + 16 * t + r15]);
        *reinterpret_cast<frag_ab*>(MtF + ((size_t)f * 64 + lane) * 8) = fr;
    } else {
        const int f2 = f - 512;
        const float* src = M + (size_t)(16 * (f2 >> 1) + r15) * 64 + 32 * (f2 & 1) + 8 * g;
        float4 a = *reinterpret_cast<const float4*>(src);
        float4 b = *reinterpret_cast<const float4*>(src + 4);
        *reinterpret_cast<frag_ab*>(MbfF + ((size_t)f2 * 64 + lane) * 8) = cvt2(a, b);
    }
}

// -------- kernel 1: fused CCAM, persistent producer/consumer ----------------
// LDS 135424 B: buf0 [0,65664), buf1 [65664,131328) (8 rows x 8208 B each,
// +4-bank row rotation); Ep[4][2][8][16] f32 at 131328. 1 block/CU.
__global__ __launch_bounds__(1024, 4) void ccam_fused(
        const float* __restrict__ x,
        const __hip_bfloat16* __restrict__ MtF,
        const __hip_bfloat16* __restrict__ MbfF,
        const float* __restrict__ aphal,
        const float* __restrict__ gamma,
        float* __restrict__ out) {
    __shared__ __align__(16) char smem[135424];
    float* Ep = (float*)(smem + 131328);   // [t][h][row][16] floats

    const int tid  = threadIdx.x;
    const int w    = tid >> 6;             // wave 0..15
    const int lane = tid & 63;
    const int g    = lane >> 4;
    const int r15  = lane & 15;
    const int r7   = r15 & 7;
    const bool prod = (w >= 8);
    const int  p    = w & 7;               // producer row id / consumer wave id

    const float alpha = aphal[0];
    const float gam   = gamma[0];

    const int t1 = p >> 1;                 // consumer phase-1 kdim-tile
    const int h1 = p & 1;                  // consumer phase-1 K-half
    const int urow0 = 4 * (g & 1);         // phase-3 update row base
    const int coff  = (g < 2) ? 0 : 32;    // phase-3 tile-pair col offset

    // producer half-fill: 8 sequential float4 loads + cvt + ds_write
    auto fill_half = [&](const float* xr, char* dst, int half) {
        float4 v[8];
#pragma unroll
        for (int i = 0; i < 8; ++i)
            v[i] = *reinterpret_cast<const float4*>(xr + half * 2048 + i * 256 + 4 * lane);
        SBAR();
#pragma unroll
        for (int i = 0; i < 8; ++i) {
            ushort4 u;
            u.x = f2bf_bits(v[i].x); u.y = f2bf_bits(v[i].y);
            u.z = f2bf_bits(v[i].z); u.w = f2bf_bits(v[i].w);
            *reinterpret_cast<ushort4*>(dst + (half * 2048 + i * 256 + 4 * lane) * 2) = u;
        }
    };

    // ---- prologue: producers fill buf0 with band blockIdx.x*8 ----
    if (prod) {
        const float* xr = x + ((size_t)(blockIdx.x * 8) * 8 + p) * 4096;
        char* dst = smem + p * 8208;
        fill_half(xr, dst, 0);
        fill_half(xr, dst, 1);
        asm volatile("s_waitcnt lgkmcnt(0)" ::: "memory");
    }
    SBAR();
    __builtin_amdgcn_s_barrier();
    SBAR();

#pragma unroll 1
    for (int bi = 0; bi < 8; ++bi) {
        const int band    = blockIdx.x * 8 + bi;
        const int rowbase = band * 8;
        char* bufc = smem + (bi & 1) * 65664;
        char* bufn = smem + ((bi + 1) & 1) * 65664;

        if (!prod) {
            // ===== phase 1: energy from bufc (round-12 body) =====
            f32x4 acc = {0.f, 0.f, 0.f, 0.f};
            {
                const char* arow = bufc + r7 * 8208;
                frag_ab Bc = load_frag(MtF + (((size_t)(64 * h1) * 4 + t1) * 64 + lane) * 8);
#pragma unroll 4
                for (int s = 0; s < 64; ++s) {
                    frag_ab Bn = Bc;
                    if (s < 63)
                        Bn = load_frag(MtF + (((size_t)(64 * h1 + s + 1) * 4 + t1) * 64 + lane) * 8);
                    frag_ab A = *reinterpret_cast<const frag_ab*>(
                        arow + (h1 * 2048 + 32 * s + 8 * g) * 2);
                    acc = MFMA16(A, Bc, acc);
                    Bc = Bn;
                }
            }
            if (g < 2) {
#pragma unroll
                for (int reg = 0; reg < 4; ++reg)
                    Ep[(((t1 * 2 + h1) * 8) + 4 * g + reg) * 16 + r15] = acc[reg];
            }
            asm volatile("s_waitcnt lgkmcnt(0)" ::: "memory");
        } else {
            // producer: first half of band bi+1's rows
            if (bi < 7) {
                const float* xr = x + ((size_t)(band + 1) * 8 + p) * 4096;
                fill_half(xr, bufn + p * 8208, 0);
            }
        }
        SBAR();
        __builtin_amdgcn_s_barrier();      // Ep visible to all consumers
        SBAR();

        if (!prod) {
            // ===== phase 2: softmax -> per-lane A-frags (round-12 body) =====
            float elo[8], ehi[8];
            {
                const int t0  = g >> 1;
                const int off = 8 * (g & 1);
                const float* e0 = Ep + ((t0 * 2 + 0) * 8 + r7) * 16 + off;
                const float* e1 = Ep + ((t0 * 2 + 1) * 8 + r7) * 16 + off;
                const float* e2 = Ep + (((t0 + 2) * 2 + 0) * 8 + r7) * 16 + off;
                const float* e3 = Ep + (((t0 + 2) * 2 + 1) * 8 + r7) * 16 + off;
                float4 a0 = *reinterpret_cast<const float4*>(e0);
                float4 a1 = *reinterpret_cast<const float4*>(e0 + 4);
                float4 b0 = *reinterpret_cast<const float4*>(e1);
                float4 b1 = *reinterpret_cast<const float4*>(e1 + 4);
                elo[0] = a0.x + b0.x; elo[1] = a0.y + b0.y; elo[2] = a0.z + b0.z; elo[3] = a0.w + b0.w;
                elo[4] = a1.x + b1.x; elo[5] = a1.y + b1.y; elo[6] = a1.z + b1.z; elo[7] = a1.w + b1.w;
                float4 c0 = *reinterpret_cast<const float4*>(e2);
                float4 c1 = *reinterpret_cast<const float4*>(e2 + 4);
                float4 d0 = *reinterpret_cast<const float4*>(e3);
                float4 d1 = *reinterpret_cast<const float4*>(e3 + 4);
                ehi[0] = c0.x + d0.x; ehi[1] = c0.y + d0.y; ehi[2] = c0.z + d0.z; ehi[3] = c0.w + d0.w;
                ehi[4] = c1.x + d1.x; ehi[5] = c1.y + d1.y; ehi[6] = c1.z + d1.z; ehi[7] = c1.w + d1.w;
            }
            float m = elo[0];
#pragma unroll
            for (int j = 1; j < 8; ++j) m = fmaxf(m, elo[j]);
#pragma unroll
            for (int j = 0; j < 8; ++j) m = fmaxf(m, ehi[j]);
            m = fmaxf(m, __shfl_xor(m, 8, 64));
            m = fmaxf(m, __shfl_xor(m, 16, 64));
            m = fmaxf(m, __shfl_xor(m, 32, 64));
#pragma unroll
            for (int j = 0; j < 8; ++j) { elo[j] = alpha * (m - elo[j]); ehi[j] = alpha * (m - ehi[j]); }
            float vm = elo[0];
#pragma unroll
            for (int j = 1; j < 8; ++j) vm = fmaxf(vm, elo[j]);
#pragma unroll
            for (int j = 0; j < 8; ++j) vm = fmaxf(vm, ehi[j]);
            vm = fmaxf(vm, __shfl_xor(vm, 8, 64));
            vm = fmaxf(vm, __shfl_xor(vm, 16, 64));
            vm = fmaxf(vm, __shfl_xor(vm, 32, 64));
            float s = 0.f;
#pragma unroll
            for (int j = 0; j < 8; ++j) { elo[j] = __expf(elo[j] - vm); s += elo[j]; }
#pragma unroll
            for (int j = 0; j < 8; ++j) { ehi[j] = __expf(ehi[j] - vm); s += ehi[j]; }
            s += __shfl_xor(s, 8, 64);
            s += __shfl_xor(s, 16, 64);
            s += __shfl_xor(s, 32, 64);
            const float sc = gam / s;
            frag_ab A0, A1;
#pragma unroll
            for (int j = 0; j < 8; ++j) {
                A0[j] = (short)f2bf_bits(elo[j] * sc);
                A1[j] = (short)f2bf_bits(ehi[j] * sc);
            }

            // ===== phase 3: in-place RMW on bufc, all-lane (round-12 body) =====
#pragma unroll 1
            for (int gi = 0; gi < 8; ++gi) {
                const int grp = 8 * p + gi;
                frag_ab B[4][2];
#pragma unroll
                for (int t = 0; t < 4; ++t)
#pragma unroll
                    for (int h = 0; h < 2; ++h)
                        B[t][h] = load_frag(MbfF + (((size_t)(4 * grp + t) * 2 + h) * 64 + lane) * 8);
                f32x4 d0 = {0.f, 0.f, 0.f, 0.f};
                f32x4 d1 = d0, d2 = d0, d3 = d0;
                d0 = MFMA16(A0, B[0][0], d0); d0 = MFMA16(A1, B[0][1], d0);
                d1 = MFMA16(A0, B[1][0], d1); d1 = MFMA16(A1, B[1][1], d1);
                d2 = MFMA16(A0, B[2][0], d2); d2 = MFMA16(A1, B[2][1], d2);
                d3 = MFMA16(A0, B[3][0], d3); d3 = MFMA16(A1, B[3][1], d3);
                f32x4 va, vb;
#pragma unroll
                for (int reg = 0; reg < 4; ++reg) {
                    va[reg] = (g < 2) ? d0[reg] : d2[reg];
                    vb[reg] = (g < 2) ? d1[reg] : d3[reg];
                }
                const int colbase = grp * 64 + coff + r15;
#pragma unroll
                for (int reg = 0; reg < 4; ++reg) {
                    unsigned short* pa =
                        (unsigned short*)(bufc + (urow0 + reg) * 8208) + colbase;
                    unsigned short* pb = pa + 16;
                    *pa = f2bf_bits(va[reg] + bf2f(*pa));
                    *pb = f2bf_bits(vb[reg] + bf2f(*pb));
                }
            }

            // ===== store: wave-private col-slice [512p, 512p+512) =====
            {
                const int cb = 512 * p;
#pragma unroll
                for (int r = 0; r < 8; ++r) {
                    const char* srow = bufc + r * 8208;
                    float* orow = out + (size_t)(rowbase + r) * 4096 + cb;
#pragma unroll
                    for (int hf = 0; hf < 2; ++hf) {
                        const int col = hf * 256 + 4 * lane;
                        ushort4 u = *reinterpret_cast<const ushort4*>(srow + (cb + col) * 2);
                        float4 vv;
                        vv.x = bf2f(u.x); vv.y = bf2f(u.y); vv.z = bf2f(u.z); vv.w = bf2f(u.w);
                        *reinterpret_cast<float4*>(orow + col) = vv;
                    }
                }
            }
            asm volatile("s_waitcnt lgkmcnt(0)" ::: "memory");
        } else {
            // producer: second half of band bi+1's rows
            if (bi < 7) {
                const float* xr = x + ((size_t)(band + 1) * 8 + p) * 4096;
                fill_half(xr, bufn + p * 8208, 1);
            }
            asm volatile("s_waitcnt lgkmcnt(0)" ::: "memory");
        }
        SBAR();
        __builtin_amdgcn_s_barrier();      // band end: bufn full, bufc free
        SBAR();
    }
}

extern "C" void kernel_launch(void* const* d_in, const int* in_sizes, int n_in,
                              void* d_out, int out_size, void* d_ws, size_t ws_size,
                              hipStream_t stream) {
    const float* x     = (const float*)d_in[0];
    const float* M     = (const float*)d_in[1];
    const float* aphal = (const float*)d_in[2];
    const float* gamma = (const float*)d_in[3];
    __hip_bfloat16* MtF  = (__hip_bfloat16*)d_ws;                  // 512 KB
    __hip_bfloat16* MbfF = (__hip_bfloat16*)d_ws + 64 * 4096;      // 512 KB

    hipLaunchKernelGGL(prep_frags, dim3(256), dim3(256), 0, stream, M, MtF, MbfF);
    hipLaunchKernelGGL(ccam_fused, dim3(256), dim3(1024), 0, stream,
                       x, MtF, MbfF, aphal, gamma, (float*)d_out);
}

// Round 16
// 142.125 us; speedup vs baseline: 1.4124x; 1.4124x over previous
//
#include <hip/hip_runtime.h>
#include <hip/hip_bf16.h>

// CCAM (fp32 in/out): x (16,1024,64,64), martx (4096,64).
// rows = B*C = 16384, N = 4096 spatial, KDIM = 64.
// energy[r][k] = sum_n x[r][n] * M[n][k]           (GEMM1, K=4096)
// att = softmax(alpha * (rowmax(energy) - energy))  (64-wide)
// out[r][n] = gamma * sum_k att[r][k]*M[n][k] + x[r][n]
//
// Round-16: round-12 winner (165.4 us, best) + ONE change: final out stores
// are NON-TEMPORAL (nt). out is write-once/never-read; letting it allocate
// in L2/L3 evicts the hot B-frag banks (2 GB of L2 re-reads/dispatch) and
// the L3-retained x stream (worth ~110 MB/dispatch). Single-variable test
// of the cache-pollution hypothesis.

using frag_ab = __attribute__((ext_vector_type(8))) short;   // 8 bf16
using f32x4   = __attribute__((ext_vector_type(4))) float;   // MFMA C/D

#define MFMA16(a, b, c) __builtin_amdgcn_mfma_f32_16x16x32_bf16((a), (b), (c), 0, 0, 0)

static __device__ __forceinline__ unsigned short f2bf_bits(float f) {
    __hip_bfloat16 h = __float2bfloat16(f);
    return *reinterpret_cast<const unsigned short*>(&h);
}
static __device__ __forceinline__ float bf2f(unsigned short u) {
    return __uint_as_float(((unsigned)u) << 16);
}
static __device__ __forceinline__ frag_ab load_frag(const __hip_bfloat16* p) {
    return *reinterpret_cast<const frag_ab*>(p);
}
static __device__ __forceinline__ frag_ab cvt2(float4 a, float4 b) {
    frag_ab r;
    r[0] = (short)f2bf_bits(a.x); r[1] = (short)f2bf_bits(a.y);
    r[2] = (short)f2bf_bits(a.z); r[3] = (short)f2bf_bits(a.w);
    r[4] = (short)f2bf_bits(b.x); r[5] = (short)f2bf_bits(b.y);
    r[6] = (short)f2bf_bits(b.z); r[7] = (short)f2bf_bits(b.w);
    return r;
}

// -------- kernel 0: build frag-linear B banks (unchanged, validated) --------
// MtF  (512 frags x 1 KB): frag f = slot*4+t, elem (lane,j) = M[32*slot+8g+j][16t+r15]
// MbfF (512 frags x 1 KB): frag f = nt*2+h,   elem (lane,j) = M[16nt+r15][32h+8g+j]
__global__ __launch_bounds__(256) void prep_frags(
        const float* __restrict__ M,
        __hip_bfloat16* __restrict__ MtF, __hip_bfloat16* __restrict__ MbfF) {
    const int w    = threadIdx.x >> 6;
    const int lane = threadIdx.x & 63;
    const int g    = lane >> 4;
    const int r15  = lane & 15;
    const int f    = blockIdx.x * 4 + w;    // 0..1023
    if (f < 512) {
        const int slot = f >> 2, t = f & 3;
        frag_ab fr;
#pragma unroll
        for (int j = 0; j < 8; ++j)
            fr[j] = (short)f2bf_bits(M[(size_t)(32 * slot + 8 * g + j) * 64 + 16 * t + r15]);
        *reinterpret_cast<frag_ab*>(MtF + ((size_t)f * 64 + lane) * 8) = fr;
    } else {
        const int f2 = f - 512;
        const float* src = M + (size_t)(16 * (f2 >> 1) + r15) * 64 + 32 * (f2 & 1) + 8 * g;
        float4 a = *reinterpret_cast<const float4*>(src);
        float4 b = *reinterpret_cast<const float4*>(src + 4);
        *reinterpret_cast<frag_ab*>(MbfF + ((size_t)f2 * 64 + lane) * 8) = cvt2(a, b);
    }
}

// -------- kernel 1: fused CCAM, 8-row blocks, sequential streams ------------
// LDS 69760 B: x image 8 rows x 8208 B (bf16, stride 4104 elems) = 65664;
//              Ep[4][2][8][16] f32 = 4096 at offset 65664.  2 blocks/CU.
__global__ __launch_bounds__(512, 2) void ccam_fused(
        const float* __restrict__ x,
        const __hip_bfloat16* __restrict__ MtF,
        const __hip_bfloat16* __restrict__ MbfF,
        const float* __restrict__ aphal,
        const float* __restrict__ gamma,
        float* __restrict__ out) {
    __shared__ __align__(16) char smem[69760];
    float* Ep = (float*)(smem + 65664);    // [t][h][row][16] floats

    const int tid  = threadIdx.x;
    const int w    = tid >> 6;             // wave 0..7
    const int lane = tid & 63;
    const int g    = lane >> 4;
    const int r15  = lane & 15;
    const int r7   = r15 & 7;
    const int rowbase = blockIdx.x * 8;

    const float alpha = aphal[0];
    const float gam   = gamma[0];

    // ===== stage: wave w reads row w sequentially, bf16 into LDS =====
    {
        const float* xr = x + (size_t)(rowbase + w) * 4096;
        char* dst = smem + w * 8208;
#pragma unroll
        for (int rnd = 0; rnd < 2; ++rnd) {
            float4 v[8];
#pragma unroll
            for (int i = 0; i < 8; ++i)
                v[i] = *reinterpret_cast<const float4*>(xr + rnd * 2048 + i * 256 + 4 * lane);
#pragma unroll
            for (int i = 0; i < 8; ++i) {
                ushort4 u;
                u.x = f2bf_bits(v[i].x); u.y = f2bf_bits(v[i].y);
                u.z = f2bf_bits(v[i].z); u.w = f2bf_bits(v[i].w);
                *reinterpret_cast<ushort4*>(dst + (rnd * 2048 + i * 256 + 4 * lane) * 2) = u;
            }
        }
    }
    __syncthreads();

    // ===== phase 1: energy from LDS; wave = (kdim-tile t1, K-half h1) =====
    const int t1 = w >> 1;
    const int h1 = w & 1;
    f32x4 acc = {0.f, 0.f, 0.f, 0.f};
    {
        const char* arow = smem + r7 * 8208;
        frag_ab Bc = load_frag(MtF + (((size_t)(64 * h1) * 4 + t1) * 64 + lane) * 8);
#pragma unroll 4
        for (int s = 0; s < 64; ++s) {
            frag_ab Bn = Bc;
            if (s < 63)
                Bn = load_frag(MtF + (((size_t)(64 * h1 + s + 1) * 4 + t1) * 64 + lane) * 8);
            frag_ab A = *reinterpret_cast<const frag_ab*>(
                arow + (h1 * 2048 + 32 * s + 8 * g) * 2);
            acc = MFMA16(A, Bc, acc);
            Bc = Bn;
        }
    }
    // Ep: rows 0..7 live in lanes g<2 (D row = 4g+reg)
    if (g < 2) {
#pragma unroll
        for (int reg = 0; reg < 4; ++reg)
            Ep[(((t1 * 2 + h1) * 8) + 4 * g + reg) * 16 + r15] = acc[reg];
    }
    __syncthreads();

    // ===== phase 2: softmax; lane builds its own phase-3 A-frag slice =====
    // lane (g,r15): row r7; k = 8g+j (A0) and 32+8g+j (A1)
    float elo[8], ehi[8];
    {
        const int t0  = g >> 1;
        const int off = 8 * (g & 1);
        const float* e0 = Ep + ((t0 * 2 + 0) * 8 + r7) * 16 + off;
        const float* e1 = Ep + ((t0 * 2 + 1) * 8 + r7) * 16 + off;
        const float* e2 = Ep + (((t0 + 2) * 2 + 0) * 8 + r7) * 16 + off;
        const float* e3 = Ep + (((t0 + 2) * 2 + 1) * 8 + r7) * 16 + off;
        float4 a0 = *reinterpret_cast<const float4*>(e0);
        float4 a1 = *reinterpret_cast<const float4*>(e0 + 4);
        float4 b0 = *reinterpret_cast<const float4*>(e1);
        float4 b1 = *reinterpret_cast<const float4*>(e1 + 4);
        elo[0] = a0.x + b0.x; elo[1] = a0.y + b0.y; elo[2] = a0.z + b0.z; elo[3] = a0.w + b0.w;
        elo[4] = a1.x + b1.x; elo[5] = a1.y + b1.y; elo[6] = a1.z + b1.z; elo[7] = a1.w + b1.w;
        float4 c0 = *reinterpret_cast<const float4*>(e2);
        float4 c1 = *reinterpret_cast<const float4*>(e2 + 4);
        float4 d0 = *reinterpret_cast<const float4*>(e3);
        float4 d1 = *reinterpret_cast<const float4*>(e3 + 4);
        ehi[0] = c0.x + d0.x; ehi[1] = c0.y + d0.y; ehi[2] = c0.z + d0.z; ehi[3] = c0.w + d0.w;
        ehi[4] = c1.x + d1.x; ehi[5] = c1.y + d1.y; ehi[6] = c1.z + d1.z; ehi[7] = c1.w + d1.w;
    }
    float m = elo[0];
#pragma unroll
    for (int j = 1; j < 8; ++j) m = fmaxf(m, elo[j]);
#pragma unroll
    for (int j = 0; j < 8; ++j) m = fmaxf(m, ehi[j]);
    m = fmaxf(m, __shfl_xor(m, 8, 64));
    m = fmaxf(m, __shfl_xor(m, 16, 64));
    m = fmaxf(m, __shfl_xor(m, 32, 64));
#pragma unroll
    for (int j = 0; j < 8; ++j) { elo[j] = alpha * (m - elo[j]); ehi[j] = alpha * (m - ehi[j]); }
    float vm = elo[0];
#pragma unroll
    for (int j = 1; j < 8; ++j) vm = fmaxf(vm, elo[j]);
#pragma unroll
    for (int j = 0; j < 8; ++j) vm = fmaxf(vm, ehi[j]);
    vm = fmaxf(vm, __shfl_xor(vm, 8, 64));
    vm = fmaxf(vm, __shfl_xor(vm, 16, 64));
    vm = fmaxf(vm, __shfl_xor(vm, 32, 64));
    float s = 0.f;
#pragma unroll
    for (int j = 0; j < 8; ++j) { elo[j] = __expf(elo[j] - vm); s += elo[j]; }
#pragma unroll
    for (int j = 0; j < 8; ++j) { ehi[j] = __expf(ehi[j] - vm); s += ehi[j]; }
    s += __shfl_xor(s, 8, 64);
    s += __shfl_xor(s, 16, 64);
    s += __shfl_xor(s, 32, 64);
    const float sc = gam / s;               // fold gamma into attention
    frag_ab A0, A1;
#pragma unroll
    for (int j = 0; j < 8; ++j) {
        A0[j] = (short)f2bf_bits(elo[j] * sc);
        A1[j] = (short)f2bf_bits(ehi[j] * sc);
    }

    // ===== phase 3: out into LDS image in place; wave w owns cols [512w,+512) =====
    // ALL-LANE update via D duplication (validated round 12).
    const int urow0 = 4 * (g & 1);          // 0 or 4
    const int coff  = (g < 2) ? 0 : 32;     // tile-pair column offset
#pragma unroll 1
    for (int gi = 0; gi < 8; ++gi) {
        const int grp = 8 * w + gi;
        frag_ab B[4][2];
#pragma unroll
        for (int t = 0; t < 4; ++t)
#pragma unroll
            for (int h = 0; h < 2; ++h)
                B[t][h] = load_frag(MbfF + (((size_t)(4 * grp + t) * 2 + h) * 64 + lane) * 8);
        f32x4 d0 = {0.f, 0.f, 0.f, 0.f};
        f32x4 d1 = d0, d2 = d0, d3 = d0;
        d0 = MFMA16(A0, B[0][0], d0); d0 = MFMA16(A1, B[0][1], d0);
        d1 = MFMA16(A0, B[1][0], d1); d1 = MFMA16(A1, B[1][1], d1);
        d2 = MFMA16(A0, B[2][0], d2); d2 = MFMA16(A1, B[2][1], d2);
        d3 = MFMA16(A0, B[3][0], d3); d3 = MFMA16(A1, B[3][1], d3);
        // per-lane select of the tile-pair this lane owns (no divergence)
        f32x4 va, vb;
#pragma unroll
        for (int reg = 0; reg < 4; ++reg) {
            va[reg] = (g < 2) ? d0[reg] : d2[reg];
            vb[reg] = (g < 2) ? d1[reg] : d3[reg];
        }
        const int colbase = grp * 64 + coff + r15;
#pragma unroll
        for (int reg = 0; reg < 4; ++reg) {
            unsigned short* pa =
                (unsigned short*)(smem + (urow0 + reg) * 8208) + colbase;
            unsigned short* pb = pa + 16;
            *pa = f2bf_bits(va[reg] + bf2f(*pa));
            *pb = f2bf_bits(vb[reg] + bf2f(*pb));
        }
    }
    __syncthreads();

    // ===== store: wave w streams row w out sequentially — NON-TEMPORAL =====
    {
        const char* srow = smem + w * 8208;
        float* orow = out + (size_t)(rowbase + w) * 4096;
#pragma unroll
        for (int i = 0; i < 16; ++i) {
            const int col = 256 * i + 4 * lane;
            ushort4 u = *reinterpret_cast<const ushort4*>(srow + col * 2);
            f32x4 v;
            v[0] = bf2f(u.x); v[1] = bf2f(u.y); v[2] = bf2f(u.z); v[3] = bf2f(u.w);
            __builtin_nontemporal_store(v, reinterpret_cast<f32x4*>(orow + col));
        }
    }
}

extern "C" void kernel_launch(void* const* d_in, const int* in_sizes, int n_in,
                              void* d_out, int out_size, void* d_ws, size_t ws_size,
                              hipStream_t stream) {
    const float* x     = (const float*)d_in[0];
    const float* M     = (const float*)d_in[1];
    const float* aphal = (const float*)d_in[2];
    const float* gamma = (const float*)d_in[3];
    __hip_bfloat16* MtF  = (__hip_bfloat16*)d_ws;                  // 512 KB
    __hip_bfloat16* MbfF = (__hip_bfloat16*)d_ws + 64 * 4096;      // 512 KB

    hipLaunchKernelGGL(prep_frags, dim3(256), dim3(256), 0, stream, M, MtF, MbfF);
    hipLaunchKernelGGL(ccam_fused, dim3(2048), dim3(512), 0, stream,
                       x, MtF, MbfF, aphal, gamma, (float*)d_out);
}